// Round 6
// baseline (240.479 us; speedup 1.0000x reference)
//
#include <hip/hip_runtime.h>

// QCausalConv1D: x[B,D,L] int8 (as int32), weight[D,W=4] int8 (as int32),
// bias[D] int8 (as int32), 4 fp32 scalar scales.
// y[b,d,l] = silu( (sum_k x[b,d,l-3+k]*w[d,k]) * in_s*w_s + bias[d]*b_s )
// out = clip(rint(y/out_s), -128, 127) as int32. B=2, D=4096, L=4096 fixed.
//
// R6: every x byte fetched from global EXACTLY once. R3/R4/R5 all plateaued
// at 81-88us (~3.3 TB/s) despite wildly different coalescing -> the
// structure-invariant costs are (a) halo duplicate reads (2x read requests
// at L1/L2/L3) and (b) write allocations churning the poison-dirtied caches.
// Fix: block = half row (512 chunks); cur chunks stay in registers, staged
// to LDS only so neighbors can read their 12B halo via conflict-free
// ds_read_b128 (lane stride 16B). Out via nontemporal stores (no L2/L3
// allocate -> no dirty-poison evictions on the write path).

#define DMASK 4095   // D-1

typedef int iv4 __attribute__((ext_vector_type(4)));

__device__ __forceinline__ int silu_requant(float y, float inv_out) {
    // silu(y) = y / (1 + exp(-y)); rintf = round-half-even matches np.round
    float e = __expf(-y);
    float s = y * __builtin_amdgcn_rcpf(1.0f + e);
    float q = rintf(s * inv_out);
    q = fminf(fmaxf(q, -128.0f), 127.0f);
    return (int)q;
}

__global__ __launch_bounds__(256) void qconv1d_kernel(
    const int* __restrict__ x,
    const int* __restrict__ w,
    const int* __restrict__ bias,
    const float* __restrict__ in_s_p,
    const float* __restrict__ w_s_p,
    const float* __restrict__ out_s_p,
    const float* __restrict__ b_s_p,
    int* __restrict__ out)
{
    __shared__ iv4 ldsv[513];          // [0] = halo chunk, [1+c] = local chunk c

    const int tid  = threadIdx.x;
    const int bid  = blockIdx.x;       // 16384 blocks
    const int row  = bid >> 1;         // b*D + d
    const int half = bid & 1;          // which half-row (512 chunks each)
    const int d    = row & DMASK;
    const int gcb  = (row << 10) + (half << 9);   // global chunk base

    const iv4* __restrict__ xv = (const iv4*)x;

    // Two coalesced 16B loads per thread -- each x byte loaded once per block.
    iv4 a0 = xv[gcb + tid];
    iv4 a1 = xv[gcb + 256 + tid];
    if (tid == 0) {
        iv4 hh = (iv4){0, 0, 0, 0};    // row start: causal zero pad
        if (half) hh = xv[gcb - 1];    // block-interior halo: one 16B load/block
        ldsv[0] = hh;
    }
    ldsv[1 + tid]       = a0;          // lane-contiguous ds_write_b128
    ldsv[1 + 256 + tid] = a1;

    // Block-uniform weight/bias/scales -> scalar loads, overlap the barrier.
    iv4 wv = ((const iv4*)w)[d];
    const float w0 = (float)wv.x, w1 = (float)wv.y, w2 = (float)wv.z, w3 = (float)wv.w;
    const float bias_i = (float)bias[d];
    const float s_xw    = in_s_p[0] * w_s_p[0];
    const float inv_out = 1.0f / out_s_p[0];
    const float bf      = bias_i * b_s_p[0];

    __syncthreads();

    // Halo for chunk (tid): previous chunk = ldsv[tid]; for chunk (256+tid):
    // ldsv[256+tid]. Both conflict-free ds_read_b128 (lane stride 16B).
    iv4 h0 = ldsv[tid];
    iv4 h1 = ldsv[256 + tid];

    iv4* __restrict__ ov = (iv4*)out;

#pragma unroll
    for (int j = 0; j < 2; ++j) {
        iv4 cur = j ? a1 : a0;
        iv4 h   = j ? h1 : h0;

        float sm3 = (float)h.y, sm2 = (float)h.z, sm1 = (float)h.w;
        float s0 = (float)cur.x, s1 = (float)cur.y,
              s2 = (float)cur.z, s3 = (float)cur.w;

        float a_0 = w0*sm3 + w1*sm2 + w2*sm1 + w3*s0;
        float a_1 = w0*sm2 + w1*sm1 + w2*s0  + w3*s1;
        float a_2 = w0*sm1 + w1*s0  + w2*s1  + w3*s2;
        float a_3 = w0*s0  + w1*s1  + w2*s2  + w3*s3;

        iv4 q;
        q.x = silu_requant(a_0 * s_xw + bf, inv_out);
        q.y = silu_requant(a_1 * s_xw + bf, inv_out);
        q.z = silu_requant(a_2 * s_xw + bf, inv_out);
        q.w = silu_requant(a_3 * s_xw + bf, inv_out);

        // Nontemporal: out is write-once -> don't allocate/evict in L2/L3.
        __builtin_nontemporal_store(q, &ov[gcb + (j << 8) + tid]);
    }
}

extern "C" void kernel_launch(void* const* d_in, const int* in_sizes, int n_in,
                              void* d_out, int out_size, void* d_ws, size_t ws_size,
                              hipStream_t stream) {
    const int*   x    = (const int*)d_in[0];
    const int*   w    = (const int*)d_in[1];
    const int*   bias = (const int*)d_in[2];
    const float* is   = (const float*)d_in[3];
    const float* ws   = (const float*)d_in[4];
    const float* os   = (const float*)d_in[5];
    const float* bs   = (const float*)d_in[6];
    int* out = (int*)d_out;

    // 2 blocks per (b,d) row: 16384 blocks x 256 threads, 8 elems/thread.
    const int rows  = out_size >> 12;      // 8192
    const int grid  = rows << 1;           // 16384
    const int block = 256;

    qconv1d_kernel<<<grid, block, 0, stream>>>(x, w, bias, is, ws, os, bs, out);
}